// Round 8
// baseline (159.223 us; speedup 1.0000x reference)
//
#include <hip/hip_runtime.h>
#include <hip/hip_bf16.h>

// Problem constants
static constexpr int kB   = 8;
static constexpr int kP   = 196;
static constexpr int kL   = 80;
static constexpr int kD1  = 2048;
static constexpr int kD2  = 300;
static constexpr int kD2p = 320;       // p2 K padded to multiple of 64
static constexpr int kATT = 1024;
static constexpr int kM   = kB * kP;   // 1568 rows of p1
static constexpr int kR2  = kB * kL;   // 640 rows of p2
static constexpr int kOut = kB * kL * kP;        // 125440 outputs
static constexpr int kASplit = 16;     // alpha: a-dim split across blocks
static constexpr int kAChunk = kATT / kASplit;   // 64
static constexpr int kLPer   = 5;      // l-values per thread (16 groups x 5 = 80)

static constexpr float kTanhScale = 2.8853900817779268f;  // 2*log2(e)

typedef __attribute__((ext_vector_type(8))) short  bf16x8;
typedef __attribute__((ext_vector_type(4))) float  f32x4;

// pack two fp32 -> packed bf16 pair (RNE), hi in upper halfword
__device__ __forceinline__ unsigned int pack_bf2(float lo, float hi) {
    union { float f; unsigned int u; } a, b; a.f = lo; b.f = hi;
    unsigned int rl = a.u + 0x7fffu + ((a.u >> 16) & 1u);
    unsigned int rh = b.u + 0x7fffu + ((b.u >> 16) & 1u);
    return (rl >> 16) | (rh & 0xffff0000u);
}

// ---------------------------------------------------------------------------
// Stage one 64x64 fp32 tile -> bf16 LDS tile [row][k], row stride 64 elems.
// Thread t: row = t>>2, k-quad = (t&3)*16 (16 elems = 4 float4 -> 2 b128).
// KSRC: true row stride / K; KT: padded K. Chunks past KSRC are zero-filled.
// row_g is the (clamped) global row for this thread.
// ---------------------------------------------------------------------------
template<int KSRC, int KT>
__device__ __forceinline__ void stage_tile(
        const float* __restrict__ G, int row_g, int k0,
        unsigned short* __restrict__ S, int tid) {
    const int row = tid >> 2;
    const int kq  = (tid & 3) * 16;
    const float* src = G + (size_t)row_g * KSRC + k0 + kq;
    unsigned int pk[8];
    #pragma unroll
    for (int j = 0; j < 4; ++j) {
        float4 f = make_float4(0.f, 0.f, 0.f, 0.f);
        if (KSRC == KT || k0 + kq + j * 4 + 4 <= KSRC)
            f = *(const float4*)(src + j * 4);
        pk[j * 2 + 0] = pack_bf2(f.x, f.y);
        pk[j * 2 + 1] = pack_bf2(f.z, f.w);
    }
    uint4* dst = (uint4*)((char*)S + row * 128 + kq * 2);
    dst[0] = make_uint4(pk[0], pk[1], pk[2], pk[3]);
    dst[1] = make_uint4(pk[4], pk[5], pk[6], pk[7]);
}

// ---------------------------------------------------------------------------
// GEMM body: C[m,n] = scale * sum_k A[m,k]*B[n,k], fp32 inputs cast to bf16
// during LDS staging. 64x64 tile, BK=64, 4 waves, 2x2 MFMA 16x16x32 per wave.
// ---------------------------------------------------------------------------
template<int KSRC, int KT>
__device__ __forceinline__ void gemm_body(
        const float* __restrict__ Ag, const float* __restrict__ Bg,
        float* __restrict__ Co, int M, float scale, int mx, int nx,
        unsigned short* As, unsigned short* Bs) {
    const int m0   = mx * 64;
    const int n0   = nx * 64;
    const int tid  = threadIdx.x;
    const int lane = tid & 63;
    const int wv   = tid >> 6;
    const int mh   = (wv >> 1) * 32;
    const int nh   = (wv & 1) * 32;
    const int arow = min(m0 + (tid >> 2), M - 1);   // clamp ragged M edge
    const int brow = n0 + (tid >> 2);               // N = 1024 exact

    f32x4 acc[2][2] = {};
    for (int k0 = 0; k0 < KT; k0 += 64) {
        __syncthreads();                 // previous iter's reads done
        stage_tile<KSRC, KT>(Ag, arow, k0, As, tid);
        stage_tile<KSRC, KT>(Bg, brow, k0, Bs, tid);
        __syncthreads();                 // tiles visible

        #pragma unroll
        for (int kk = 0; kk < 2; ++kk) {
            bf16x8 af[2], bf[2];
            #pragma unroll
            for (int i = 0; i < 2; ++i) {
                int r = mh + i * 16 + (lane & 15);
                af[i] = *(const bf16x8*)((const char*)As + r * 128 + kk * 64 + (lane >> 4) * 16);
            }
            #pragma unroll
            for (int j = 0; j < 2; ++j) {
                int r = nh + j * 16 + (lane & 15);
                bf[j] = *(const bf16x8*)((const char*)Bs + r * 128 + kk * 64 + (lane >> 4) * 16);
            }
            #pragma unroll
            for (int i = 0; i < 2; ++i)
                #pragma unroll
                for (int j = 0; j < 2; ++j)
                    acc[i][j] = __builtin_amdgcn_mfma_f32_16x16x32_bf16(
                                    af[i], bf[j], acc[i][j], 0, 0, 0);
        }
    }

    // C/D layout: col = lane&15, row = (lane>>4)*4 + reg   [m89/m91 verified]
    #pragma unroll
    for (int i = 0; i < 2; ++i)
        #pragma unroll
        for (int j = 0; j < 2; ++j)
            #pragma unroll
            for (int r = 0; r < 4; ++r) {
                int m = m0 + mh + i * 16 + (lane >> 4) * 4 + r;
                int n = n0 + nh + j * 16 + (lane & 15);
                if (m < M) Co[(size_t)m * kATT + n] = scale * acc[i][j][r];
            }
}

// ---------------------------------------------------------------------------
// Mega kernel: [0,160) p2 GEMM (K=300 pad 320) | [160,560) p1 GEMM (K=2048,
// pre-scaled by 2log2e) | [560,624) vbeta partials (v/beta pre-zeroed).
// ---------------------------------------------------------------------------
static constexpr int kP2Blocks = (kR2 / 64) * (kATT / 64);       // 160
static constexpr int kP1Blocks = ((kM + 63) / 64) * (kATT / 64); // 400

__global__ __launch_bounds__(256) void mega_kernel(
        const float* __restrict__ x2, const float* __restrict__ W2,
        float* __restrict__ p2w,
        const float* __restrict__ x1, const float* __restrict__ W1,
        float* __restrict__ p1w,
        const float* __restrict__ Wh, const float* __restrict__ wt,
        const float* __restrict__ bh, const float* __restrict__ bt,
        float* __restrict__ v, float* __restrict__ beta) {
    __shared__ unsigned short As[64 * 64];   // 8 KB
    __shared__ unsigned short Bs[64 * 64];   // 8 KB
    const int bid = blockIdx.x;
    if (bid < kP2Blocks) {
        gemm_body<kD2, kD2p>(x2, W2, p2w, kR2, 1.0f,
                             bid % (kR2 / 64), bid / (kR2 / 64), As, Bs);
    } else if (bid < kP2Blocks + kP1Blocks) {
        int l = bid - kP2Blocks;
        gemm_body<kD1, kD1>(x1, W1, p1w, kM, kTanhScale,
                            l % ((kM + 63) / 64), l / ((kM + 63) / 64), As, Bs);
    } else {                                 // ---- vbeta (64 blocks)
        int vb = bid - kP2Blocks - kP1Blocks;
        int ax = vb & 3;                     // a-chunk of 256
        int c0 = (vb >> 2) * 64;             // c-slice of 64
        int a  = ax * 256 + threadIdx.x;
        float acc = 0.0f;
        #pragma unroll 8
        for (int c = c0; c < c0 + 64; ++c)
            acc = fmaf(wt[c], Wh[(size_t)c * kATT + a], acc);
        atomicAdd(&v[a], acc);
        if (ax == 0 && threadIdx.x < 64) {
            int c = c0 + threadIdx.x;
            float pb = wt[c] * bh[c];
            #pragma unroll
            for (int off = 32; off > 0; off >>= 1)
                pb += __shfl_down(pb, off, 64);
            if (threadIdx.x == 0) {
                if (c0 == 0) pb += bt[0];
                atomicAdd(beta, pb);
            }
        }
    }
}

// ---------------------------------------------------------------------------
// alpha partial, register-blocked streaming, atomic-free split-K.
//   p1 pre-scaled by 2log2(e): sum_a v*tanh = sumV - 2*sum_a v*rcp(exp2(u*w)+1)
// grid (13, kB, kASplit); block 256 = 16 p x 16 l-groups (5 l each).
// ---------------------------------------------------------------------------
__global__ __launch_bounds__(256) void alpha_kernel(
        const float* __restrict__ p1, const float* __restrict__ p2,
        const float* __restrict__ v, float* __restrict__ part) {
    __shared__ float vs[kAChunk];            // 256 B
    __shared__ float sred;
    const int b     = blockIdx.y;
    const int as    = blockIdx.z;
    const int aBase = as * kAChunk;
    const int p0    = blockIdx.x * 16;
    const int tid   = threadIdx.x;
    const int tp    = tid & 15;              // p lane -> 16-line u loads
    const int lg    = tid >> 4;              // l-group: l = lg*5 + j

    if (tid < kAChunk) vs[tid] = v[aBase + tid];
    __syncthreads();
    if (tid < 64) {                          // sumV of this chunk (kAChunk==64)
        float s = vs[tid];
        #pragma unroll
        for (int off = 32; off > 0; off >>= 1)
            s += __shfl_down(s, off, 64);
        if (tid == 0) sred = s;
    }
    __syncthreads();
    const float sumV = sred;

    const int p   = p0 + tp;
    const int gr1 = b * kP + min(p, kP - 1);
    const float* pu = p1 + (size_t)gr1 * kATT + aBase;
    const float* pw = p2 + ((size_t)(b * kL + lg * kLPer)) * kATT + aBase;

    float acc[kLPer] = {};
    #pragma unroll 2
    for (int a4 = 0; a4 < kAChunk / 4; ++a4) {
        float4 u  = *(const float4*)(pu + a4 * 4);
        float4 vv = *(const float4*)&vs[a4 * 4];
        #pragma unroll
        for (int j = 0; j < kLPer; ++j) {
            float4 w = *(const float4*)(pw + (size_t)j * kATT + a4 * 4);
            acc[j] = fmaf(vv.x, __builtin_amdgcn_rcpf(__builtin_amdgcn_exp2f(u.x * w.x) + 1.0f), acc[j]);
            acc[j] = fmaf(vv.y, __builtin_amdgcn_rcpf(__builtin_amdgcn_exp2f(u.y * w.y) + 1.0f), acc[j]);
            acc[j] = fmaf(vv.z, __builtin_amdgcn_rcpf(__builtin_amdgcn_exp2f(u.z * w.z) + 1.0f), acc[j]);
            acc[j] = fmaf(vv.w, __builtin_amdgcn_rcpf(__builtin_amdgcn_exp2f(u.w * w.w) + 1.0f), acc[j]);
        }
    }
    if (p < kP) {
        float* po = part + (size_t)as * kOut + ((size_t)b * kL + lg * kLPer) * kP + p;
        #pragma unroll
        for (int j = 0; j < kLPer; ++j)
            po[(size_t)j * kP] = sumV - 2.0f * acc[j];
    }
}

// ---------------------------------------------------------------------------
// out[i] = beta + sum_s part[s][i]
// ---------------------------------------------------------------------------
__global__ __launch_bounds__(256) void reduce_kernel(
        const float* __restrict__ part, const float* __restrict__ beta,
        float* __restrict__ out) {
    int i = blockIdx.x * 256 + threadIdx.x;
    if (i < kOut) {
        float s = beta[0];
        #pragma unroll
        for (int r = 0; r < kASplit; ++r)
            s += part[(size_t)r * kOut + i];
        out[i] = s;
    }
}

// ---------------------------------------------------------------------------
extern "C" void kernel_launch(void* const* d_in, const int* in_sizes, int n_in,
                              void* d_out, int out_size, void* d_ws, size_t ws_size,
                              hipStream_t stream) {
    const float* x1 = (const float*)d_in[0];
    const float* x2 = (const float*)d_in[1];
    const float* W1 = (const float*)d_in[2];
    const float* W2 = (const float*)d_in[3];
    const float* Wh = (const float*)d_in[4];
    const float* bh = (const float*)d_in[5];
    const float* wt = (const float*)d_in[6];
    const float* bt = (const float*)d_in[7];
    float* out = (float*)d_out;

    // workspace (floats): v[1024] | beta pad->1088 | p2w[640*1024]
    // | p1w[1568*1024] | part[kASplit*kOut]   (~17 MB total)
    float* ws   = (float*)d_ws;
    float* v    = ws;
    float* beta = ws + 1024;
    float* p2w  = ws + 1088;
    float* p1w  = p2w + (size_t)kR2 * kATT;
    float* part = p1w + (size_t)kM * kATT;

    hipMemsetAsync(ws, 0, 1088 * sizeof(float), stream);

    mega_kernel<<<dim3(kP2Blocks + kP1Blocks + 64), 256, 0, stream>>>(
        x2, W2, p2w, x1, W1, p1w, Wh, wt, bh, bt, v, beta);
    alpha_kernel<<<dim3((kP + 15) / 16, kB, kASplit), 256, 0, stream>>>(
        p1w, p2w, v, part);
    reduce_kernel<<<dim3((kOut + 255) / 256), 256, 0, stream>>>(part, beta, out);
}